// Round 1
// baseline (416.114 us; speedup 1.0000x reference)
//
#include <hip/hip_runtime.h>

typedef __bf16 bf16_t;
typedef bf16_t bf16x8 __attribute__((ext_vector_type(8)));
typedef float f32x4 __attribute__((ext_vector_type(4)));

typedef const __attribute__((address_space(1))) void* as1_cvp;
typedef __attribute__((address_space(3))) void* as3_vp;

__device__ __forceinline__ void gload16(const void* g, void* l) {
  __builtin_amdgcn_global_load_lds((as1_cvp)g, (as3_vp)l, 16, 0, 0);
}

// ---------------------------------------------------------------- convert f32 -> bf16
__global__ __launch_bounds__(256) void cvt_kernel(const float* __restrict__ src,
                                                  bf16_t* __restrict__ dst, int n8) {
  int i = blockIdx.x * 256 + threadIdx.x;
  if (i >= n8) return;
  int idx = i * 8;
  float4 a = *(const float4*)(src + idx);
  float4 b = *(const float4*)(src + idx + 4);
  bf16x8 o;
  o[0] = (bf16_t)a.x; o[1] = (bf16_t)a.y; o[2] = (bf16_t)a.z; o[3] = (bf16_t)a.w;
  o[4] = (bf16_t)b.x; o[5] = (bf16_t)b.y; o[6] = (bf16_t)b.z; o[7] = (bf16_t)b.w;
  *(bf16x8*)(dst + idx) = o;
}

// ---------------------------------------------------------------- GEMM  C = A * B^T
// A: MxK bf16 row-major, B: NxK bf16 row-major (i.e. B^T input), C: MxN f32
// 128x128 tile, BK=64, 256 threads (4 waves, 2x2), m97 structure.
#define BM 128
#define BN 128
#define BK 64
__global__ __launch_bounds__(256, 2) void gemm_bt(const bf16_t* __restrict__ A,
                                                  const bf16_t* __restrict__ B,
                                                  float* __restrict__ C,
                                                  int M, int N, int K) {
  __shared__ alignas(16) bf16_t As[BM * BK];
  __shared__ alignas(16) bf16_t Bs[BN * BK];
  const int t = threadIdx.x;
  const int lane = t & 63, w = t >> 6;
  const int wm = w >> 1, wn = w & 1;
  const int lr = lane & 15, lg = lane >> 4;
  const int m0 = blockIdx.y * BM, n0 = blockIdx.x * BN;
  const int srow = t >> 3, scol = (t & 7) * 8;  // staging: row within 32-group, col chunk

  f32x4 acc[4][4] = {};

  for (int kb = 0; kb < K; kb += BK) {
    __syncthreads();
#pragma unroll
    for (int i = 0; i < 4; ++i) {
      gload16(A + (size_t)(m0 + srow + 32 * i) * K + kb + scol, As + i * 2048 + t * 8);
      gload16(B + (size_t)(n0 + srow + 32 * i) * K + kb + scol, Bs + i * 2048 + t * 8);
    }
    __syncthreads();
#pragma unroll
    for (int kk = 0; kk < 2; ++kk) {
      const int ko = kk * 32 + lg * 8;
      bf16x8 af[4], bfr[4];
#pragma unroll
      for (int r = 0; r < 4; ++r)
        af[r] = *(const bf16x8*)(As + (wm * 64 + r * 16 + lr) * BK + ko);
#pragma unroll
      for (int c = 0; c < 4; ++c)
        bfr[c] = *(const bf16x8*)(Bs + (wn * 64 + c * 16 + lr) * BK + ko);
#pragma unroll
      for (int r = 0; r < 4; ++r)
#pragma unroll
        for (int c = 0; c < 4; ++c)
          acc[r][c] = __builtin_amdgcn_mfma_f32_16x16x32_bf16(af[r], bfr[c], acc[r][c], 0, 0, 0);
    }
  }
  // epilogue: D layout row=(lane>>4)*4+b, col=lane&15
#pragma unroll
  for (int r = 0; r < 4; ++r)
#pragma unroll
    for (int c = 0; c < 4; ++c)
#pragma unroll
      for (int b = 0; b < 4; ++b)
        C[(size_t)(m0 + wm * 64 + r * 16 + lg * 4 + b) * N + n0 + wn * 64 + c * 16 + lr] =
            acc[r][c][b];
}

// ---------------------------------------------------------------- RoPE + relayout (Q or K)
// src: qkv f32 (4096 x 3072), dst: (B, nh, S, HD) bf16
__global__ __launch_bounds__(256) void rope_kernel(const float* __restrict__ qkv,
                                                   const float* __restrict__ cs,
                                                   const float* __restrict__ sn,
                                                   bf16_t* __restrict__ dst,
                                                   int nh, int lognh, int col_off) {
  int idx = blockIdx.x * 256 + threadIdx.x;
  int chunk = idx & 15;            // 16 chunks of 8 elems (=4 pairs) over HD=128
  int s = (idx >> 4) & 2047;
  int hh = (idx >> 15) & (nh - 1);
  int bb = idx >> (15 + lognh);
  const float* src = qkv + (size_t)(bb * 2048 + s) * 3072 + col_off + hh * 128 + chunk * 8;
  float4 x0 = *(const float4*)src;
  float4 x1 = *(const float4*)(src + 4);
  float4 c4 = *(const float4*)(cs + s * 64 + chunk * 4);
  float4 s4 = *(const float4*)(sn + s * 64 + chunk * 4);
  bf16x8 o;
  o[0] = (bf16_t)(x0.x * c4.x - x0.y * s4.x);
  o[1] = (bf16_t)(x0.x * s4.x + x0.y * c4.x);
  o[2] = (bf16_t)(x0.z * c4.y - x0.w * s4.y);
  o[3] = (bf16_t)(x0.z * s4.y + x0.w * c4.y);
  o[4] = (bf16_t)(x1.x * c4.z - x1.y * s4.z);
  o[5] = (bf16_t)(x1.x * s4.z + x1.y * c4.z);
  o[6] = (bf16_t)(x1.z * c4.w - x1.w * s4.w);
  o[7] = (bf16_t)(x1.z * s4.w + x1.w * c4.w);
  *(bf16x8*)(dst + ((size_t)(bb * nh + hh) * 2048 + s) * 128 + chunk * 8) = o;
}

// ---------------------------------------------------------------- V transpose: (B,S,[v cols]) -> (B,NKV,HD,S) bf16
__global__ __launch_bounds__(256) void vt_kernel(const float* __restrict__ qkv,
                                                 bf16_t* __restrict__ vt) {
  __shared__ bf16_t tile[64][128];
  int t = threadIdx.x;
  int bid = blockIdx.x;  // (bb*4 + kh)*32 + st
  int st = bid & 31;
  int kh = (bid >> 5) & 3;
  int bb = bid >> 7;
  const float* src = qkv + (size_t)(bb * 2048 + st * 64) * 3072 + 2560 + kh * 128;
#pragma unroll
  for (int j = 0; j < 8; ++j) {
    int id = t + 256 * j;  // 2048 float4 chunks: 64 rows x 32 fvec
    int sr = id >> 5, dv = id & 31;
    float4 x = *(const float4*)(src + (size_t)sr * 3072 + dv * 4);
    tile[sr][dv * 4 + 0] = (bf16_t)x.x;
    tile[sr][dv * 4 + 1] = (bf16_t)x.y;
    tile[sr][dv * 4 + 2] = (bf16_t)x.z;
    tile[sr][dv * 4 + 3] = (bf16_t)x.w;
  }
  __syncthreads();
  bf16_t* dst = vt + (size_t)(bb * 4 + kh) * 128 * 2048 + st * 64;
#pragma unroll
  for (int j = 0; j < 4; ++j) {
    int id = t + 256 * j;  // 1024 chunks of 8 bf16: 128 d x 8 s-chunks
    int d = id >> 3, sc8 = id & 7;
    bf16x8 v;
#pragma unroll
    for (int e = 0; e < 8; ++e) v[e] = tile[sc8 * 8 + e][d];
    *(bf16x8*)(dst + (size_t)d * 2048 + sc8 * 8) = v;
  }
}

// ---------------------------------------------------------------- flash attention
// Q:(B,NH,S,HD) K:(B,NKV,S,HD) Vt:(B,NKV,HD,S) all bf16 -> O:(B*S, H) bf16
// 4 waves/block, each wave owns 16 q-rows; KVBLK=64 staged in LDS.
#define KVB 64
__global__ __launch_bounds__(256, 2) void attn_kernel(const bf16_t* __restrict__ Q,
                                                      const bf16_t* __restrict__ Kg,
                                                      const bf16_t* __restrict__ Vg,
                                                      bf16_t* __restrict__ O) {
  __shared__ alignas(16) bf16_t Ks[KVB * 128];   // 16KB  [key][d]
  __shared__ alignas(16) bf16_t Vs[128 * KVB];   // 16KB  [d][key]
  __shared__ alignas(16) bf16_t Ps[4][16 * KVB]; // 8KB   per-wave P tile [q][key]
  const int t = threadIdx.x;
  const int lane = t & 63, w = t >> 6;
  const int lr = lane & 15, lg = lane >> 4;
  const int bid = blockIdx.x;
  const int qt = bid & 31;
  const int h = (bid >> 5) & 15;
  const int bb = bid >> 9;
  const int kvh = h >> 2;

  const bf16_t* Qh = Q + (((size_t)bb * 16 + h) * 2048 + qt * 64 + w * 16) * 128;
  const bf16_t* Kh = Kg + ((size_t)bb * 4 + kvh) * 2048 * 128;
  const bf16_t* Vh = Vg + ((size_t)bb * 4 + kvh) * 128 * 2048;

  // hoist Q fragments (16 rows x 128 d)
  bf16x8 qf[4];
#pragma unroll
  for (int kc = 0; kc < 4; ++kc)
    qf[kc] = *(const bf16x8*)(Qh + lr * 128 + kc * 32 + lg * 8);

  f32x4 o[8] = {};
  float m2[4] = {-1e30f, -1e30f, -1e30f, -1e30f};
  float ls[4] = {0.f, 0.f, 0.f, 0.f};
  const float sm = 0.08838834764831845f * 1.44269504088896f;  // 1/sqrt(128) * log2(e)

  for (int kb = 0; kb < 2048; kb += KVB) {
    __syncthreads();
#pragma unroll
    for (int i = 0; i < 4; ++i) {
      gload16(Kh + (size_t)(kb + i * 16 + (t >> 4)) * 128 + (t & 15) * 8, Ks + i * 2048 + t * 8);
      gload16(Vh + (size_t)(i * 32 + (t >> 3)) * 2048 + kb + (t & 7) * 8, Vs + i * 2048 + t * 8);
    }
    __syncthreads();

    // QK^T: 4 col-groups x 4 k-chunks
    f32x4 sc[4];
#pragma unroll
    for (int cg = 0; cg < 4; ++cg) {
      f32x4 a = {};
#pragma unroll
      for (int kc = 0; kc < 4; ++kc) {
        bf16x8 kf = *(const bf16x8*)(Ks + (cg * 16 + lr) * 128 + kc * 32 + lg * 8);
        a = __builtin_amdgcn_mfma_f32_16x16x32_bf16(qf[kc], kf, a, 0, 0, 0);
      }
      sc[cg] = a * sm;  // now in log2 units
    }
    // online softmax (rows live in 16-lane groups; shuffle masks 1,2,4,8 stay in-group)
    float mx[4];
#pragma unroll
    for (int b = 0; b < 4; ++b) {
      float v = fmaxf(fmaxf(sc[0][b], sc[1][b]), fmaxf(sc[2][b], sc[3][b]));
      v = fmaxf(v, __shfl_xor(v, 1));
      v = fmaxf(v, __shfl_xor(v, 2));
      v = fmaxf(v, __shfl_xor(v, 4));
      v = fmaxf(v, __shfl_xor(v, 8));
      mx[b] = v;
    }
    float resc[4];
#pragma unroll
    for (int b = 0; b < 4; ++b) {
      float mn = fmaxf(m2[b], mx[b]);
      resc[b] = exp2f(m2[b] - mn);
      m2[b] = mn;
    }
    float rs[4] = {0.f, 0.f, 0.f, 0.f};
#pragma unroll
    for (int cg = 0; cg < 4; ++cg)
#pragma unroll
      for (int b = 0; b < 4; ++b) {
        float p = exp2f(sc[cg][b] - m2[b]);
        sc[cg][b] = p;
        rs[b] += p;
      }
#pragma unroll
    for (int b = 0; b < 4; ++b) {
      float v = rs[b];
      v += __shfl_xor(v, 1);
      v += __shfl_xor(v, 2);
      v += __shfl_xor(v, 4);
      v += __shfl_xor(v, 8);
      ls[b] = ls[b] * resc[b] + v;
    }
#pragma unroll
    for (int d = 0; d < 8; ++d)
#pragma unroll
      for (int b = 0; b < 4; ++b) o[d][b] *= resc[b];

    // P: D-layout -> LDS row-major [16][64] (wave-private)
    bf16_t* P = Ps[w];
#pragma unroll
    for (int cg = 0; cg < 4; ++cg)
#pragma unroll
      for (int b = 0; b < 4; ++b)
        P[(lg * 4 + b) * KVB + cg * 16 + lr] = (bf16_t)sc[cg][b];

    bf16x8 pf[2];
#pragma unroll
    for (int kk = 0; kk < 2; ++kk)
      pf[kk] = *(const bf16x8*)(P + lr * KVB + kk * 32 + lg * 8);
#pragma unroll
    for (int d = 0; d < 8; ++d) {
#pragma unroll
      for (int kk = 0; kk < 2; ++kk) {
        bf16x8 vf = *(const bf16x8*)(Vs + (d * 16 + lr) * KVB + kk * 32 + lg * 8);
        o[d] = __builtin_amdgcn_mfma_f32_16x16x32_bf16(pf[kk], vf, o[d], 0, 0, 0);
      }
    }
  }

  // epilogue: divide by l, write (B*S, H) bf16
  const size_t q0 = (size_t)bb * 2048 + qt * 64 + w * 16;
#pragma unroll
  for (int d = 0; d < 8; ++d)
#pragma unroll
    for (int b = 0; b < 4; ++b) {
      float val = o[d][b] / ls[b];
      O[(q0 + lg * 4 + b) * 2048 + h * 128 + d * 16 + lr] = (bf16_t)val;
    }
}

// ---------------------------------------------------------------- launch
extern "C" void kernel_launch(void* const* d_in, const int* in_sizes, int n_in,
                              void* d_out, int out_size, void* d_ws, size_t ws_size,
                              hipStream_t stream) {
  const float* hs = (const float*)d_in[0];
  const float* fc = (const float*)d_in[1];
  const float* fs = (const float*)d_in[2];
  const float* Wq = (const float*)d_in[3];
  const float* Wk = (const float*)d_in[4];
  const float* Wv = (const float*)d_in[5];
  const float* Wo = (const float*)d_in[6];
  float* out = (float*)d_out;

  char* ws = (char*)d_ws;
  bf16_t* hs_b = (bf16_t*)ws;                      // 16,777,216 B
  bf16_t* wcat = (bf16_t*)(ws + 16777216);         // 12,582,912 B (3072x2048)
  bf16_t* wo_b = (bf16_t*)(ws + 29360128);         //  8,388,608 B
  float* qkv = (float*)(ws + 37748736);            // 50,331,648 B (4096x3072)
  bf16_t* qr = (bf16_t*)(ws + 88080384);           // 16,777,216 B
  bf16_t* kr = (bf16_t*)(ws + 104857600);          //  4,194,304 B
  bf16_t* vt = (bf16_t*)(ws + 109051904);          //  4,194,304 B
  bf16_t* ao = (bf16_t*)(ws + 113246208);          // 16,777,216 B  (total ~124 MB)

  cvt_kernel<<<8388608 / 8 / 256, 256, 0, stream>>>(hs, hs_b, 8388608 / 8);
  cvt_kernel<<<4194304 / 8 / 256, 256, 0, stream>>>(Wq, wcat, 4194304 / 8);
  cvt_kernel<<<1048576 / 8 / 256, 256, 0, stream>>>(Wk, wcat + 4194304, 1048576 / 8);
  cvt_kernel<<<1048576 / 8 / 256, 256, 0, stream>>>(Wv, wcat + 5242880, 1048576 / 8);
  cvt_kernel<<<4194304 / 8 / 256, 256, 0, stream>>>(Wo, wo_b, 4194304 / 8);

  dim3 g1(3072 / BN, 4096 / BM);
  gemm_bt<<<g1, 256, 0, stream>>>(hs_b, wcat, qkv, 4096, 3072, 2048);

  rope_kernel<<<4096, 256, 0, stream>>>(qkv, fc, fs, qr, 16, 4, 0);
  rope_kernel<<<1024, 256, 0, stream>>>(qkv, fc, fs, kr, 4, 2, 2048);
  vt_kernel<<<256, 256, 0, stream>>>(qkv, vt);

  attn_kernel<<<1024, 256, 0, stream>>>(qr, kr, vt, ao);

  dim3 g2(2048 / BN, 4096 / BM);
  gemm_bt<<<g2, 256, 0, stream>>>(ao, wo_b, out, 4096, 2048, 2048);
}

// Round 2
// 308.084 us; speedup vs baseline: 1.3507x; 1.3507x over previous
//
#include <hip/hip_runtime.h>

typedef __bf16 bf16_t;
typedef bf16_t bf16x8 __attribute__((ext_vector_type(8)));
typedef float f32x4 __attribute__((ext_vector_type(4)));

typedef const __attribute__((address_space(1))) void* as1_cvp;
typedef __attribute__((address_space(3))) void* as3_vp;

__device__ __forceinline__ void gload16(const void* g, void* l) {
  __builtin_amdgcn_global_load_lds((as1_cvp)g, (as3_vp)l, 16, 0, 0);
}

// ---------------------------------------------------------------- convert f32 -> bf16
__global__ __launch_bounds__(256) void cvt_kernel(const float* __restrict__ src,
                                                  bf16_t* __restrict__ dst, int n8) {
  int i = blockIdx.x * 256 + threadIdx.x;
  if (i >= n8) return;
  int idx = i * 8;
  float4 a = *(const float4*)(src + idx);
  float4 b = *(const float4*)(src + idx + 4);
  bf16x8 o;
  o[0] = (bf16_t)a.x; o[1] = (bf16_t)a.y; o[2] = (bf16_t)a.z; o[3] = (bf16_t)a.w;
  o[4] = (bf16_t)b.x; o[5] = (bf16_t)b.y; o[6] = (bf16_t)b.z; o[7] = (bf16_t)b.w;
  *(bf16x8*)(dst + idx) = o;
}

// ---------------------------------------------------------------- GEMM  C = A * B^T
// A: MxK bf16 row-major, B: NxK bf16 row-major (i.e. B^T input), C: MxN f32
// 128x128 tile, BK=64, 256 threads (4 waves, 2x2), m97 structure.
#define BM 128
#define BN 128
#define BK 64
__global__ __launch_bounds__(256, 2) void gemm_bt(const bf16_t* __restrict__ A,
                                                  const bf16_t* __restrict__ B,
                                                  float* __restrict__ C,
                                                  int M, int N, int K) {
  __shared__ alignas(16) bf16_t As[BM * BK];
  __shared__ alignas(16) bf16_t Bs[BN * BK];
  const int t = threadIdx.x;
  const int lane = t & 63, w = t >> 6;
  const int wm = w >> 1, wn = w & 1;
  const int lr = lane & 15, lg = lane >> 4;
  const int m0 = blockIdx.y * BM, n0 = blockIdx.x * BN;
  const int srow = t >> 3, scol = (t & 7) * 8;  // staging: row within 32-group, col chunk

  f32x4 acc[4][4] = {};

  for (int kb = 0; kb < K; kb += BK) {
    __syncthreads();
#pragma unroll
    for (int i = 0; i < 4; ++i) {
      gload16(A + (size_t)(m0 + srow + 32 * i) * K + kb + scol, As + i * 2048 + t * 8);
      gload16(B + (size_t)(n0 + srow + 32 * i) * K + kb + scol, Bs + i * 2048 + t * 8);
    }
    __syncthreads();
#pragma unroll
    for (int kk = 0; kk < 2; ++kk) {
      const int ko = kk * 32 + lg * 8;
      bf16x8 af[4], bfr[4];
#pragma unroll
      for (int r = 0; r < 4; ++r)
        af[r] = *(const bf16x8*)(As + (wm * 64 + r * 16 + lr) * BK + ko);
#pragma unroll
      for (int c = 0; c < 4; ++c)
        bfr[c] = *(const bf16x8*)(Bs + (wn * 64 + c * 16 + lr) * BK + ko);
#pragma unroll
      for (int r = 0; r < 4; ++r)
#pragma unroll
        for (int c = 0; c < 4; ++c)
          acc[r][c] = __builtin_amdgcn_mfma_f32_16x16x32_bf16(af[r], bfr[c], acc[r][c], 0, 0, 0);
    }
  }
  // epilogue: D layout row=(lane>>4)*4+b, col=lane&15
#pragma unroll
  for (int r = 0; r < 4; ++r)
#pragma unroll
    for (int c = 0; c < 4; ++c)
#pragma unroll
      for (int b = 0; b < 4; ++b)
        C[(size_t)(m0 + wm * 64 + r * 16 + lg * 4 + b) * N + n0 + wn * 64 + c * 16 + lr] =
            acc[r][c][b];
}

// ---------------------------------------------------------------- RoPE + relayout (Q or K)
// src: qkv f32 (4096 x 3072), dst: (B, nh, S, HD) bf16
__global__ __launch_bounds__(256) void rope_kernel(const float* __restrict__ qkv,
                                                   const float* __restrict__ cs,
                                                   const float* __restrict__ sn,
                                                   bf16_t* __restrict__ dst,
                                                   int nh, int lognh, int col_off) {
  int idx = blockIdx.x * 256 + threadIdx.x;
  int chunk = idx & 15;            // 16 chunks of 8 elems (=4 pairs) over HD=128
  int s = (idx >> 4) & 2047;
  int hh = (idx >> 15) & (nh - 1);
  int bb = idx >> (15 + lognh);
  const float* src = qkv + (size_t)(bb * 2048 + s) * 3072 + col_off + hh * 128 + chunk * 8;
  float4 x0 = *(const float4*)src;
  float4 x1 = *(const float4*)(src + 4);
  float4 c4 = *(const float4*)(cs + s * 64 + chunk * 4);
  float4 s4 = *(const float4*)(sn + s * 64 + chunk * 4);
  bf16x8 o;
  o[0] = (bf16_t)(x0.x * c4.x - x0.y * s4.x);
  o[1] = (bf16_t)(x0.x * s4.x + x0.y * c4.x);
  o[2] = (bf16_t)(x0.z * c4.y - x0.w * s4.y);
  o[3] = (bf16_t)(x0.z * s4.y + x0.w * c4.y);
  o[4] = (bf16_t)(x1.x * c4.z - x1.y * s4.z);
  o[5] = (bf16_t)(x1.x * s4.z + x1.y * c4.z);
  o[6] = (bf16_t)(x1.z * c4.w - x1.w * s4.w);
  o[7] = (bf16_t)(x1.z * s4.w + x1.w * c4.w);
  *(bf16x8*)(dst + ((size_t)(bb * nh + hh) * 2048 + s) * 128 + chunk * 8) = o;
}

// ---------------------------------------------------------------- V transpose: (B,S,[v cols]) -> (B,NKV,HD,S) bf16
__global__ __launch_bounds__(256) void vt_kernel(const float* __restrict__ qkv,
                                                 bf16_t* __restrict__ vt) {
  __shared__ bf16_t tile[64][128];
  int t = threadIdx.x;
  int bid = blockIdx.x;  // (bb*4 + kh)*32 + st
  int st = bid & 31;
  int kh = (bid >> 5) & 3;
  int bb = bid >> 7;
  const float* src = qkv + (size_t)(bb * 2048 + st * 64) * 3072 + 2560 + kh * 128;
#pragma unroll
  for (int j = 0; j < 8; ++j) {
    int id = t + 256 * j;  // 2048 float4 chunks: 64 rows x 32 fvec
    int sr = id >> 5, dv = id & 31;
    float4 x = *(const float4*)(src + (size_t)sr * 3072 + dv * 4);
    tile[sr][dv * 4 + 0] = (bf16_t)x.x;
    tile[sr][dv * 4 + 1] = (bf16_t)x.y;
    tile[sr][dv * 4 + 2] = (bf16_t)x.z;
    tile[sr][dv * 4 + 3] = (bf16_t)x.w;
  }
  __syncthreads();
  bf16_t* dst = vt + (size_t)(bb * 4 + kh) * 128 * 2048 + st * 64;
#pragma unroll
  for (int j = 0; j < 4; ++j) {
    int id = t + 256 * j;  // 1024 chunks of 8 bf16: 128 d x 8 s-chunks
    int d = id >> 3, sc8 = id & 7;
    bf16x8 v;
#pragma unroll
    for (int e = 0; e < 8; ++e) v[e] = tile[sc8 * 8 + e][d];
    *(bf16x8*)(dst + (size_t)d * 2048 + sc8 * 8) = v;
  }
}

// ---------------------------------------------------------------- flash attention
// Q:(B,NH,S,HD) K:(B,NKV,S,HD) Vt:(B,NKV,HD,S) all bf16 -> O:(B*S, H) bf16
// 4 waves/block, each wave owns 16 q-rows; KVBLK=64 staged in LDS.
// All LDS tiles XOR-swizzled (T2, rule #21): linear global_load_lds dest +
// pre-swizzled global source; ds_read applies elem_off ^= (row&7)*8.
#define KVB 64
__global__ __launch_bounds__(256, 2) void attn_kernel(const bf16_t* __restrict__ Q,
                                                      const bf16_t* __restrict__ Kg,
                                                      const bf16_t* __restrict__ Vg,
                                                      bf16_t* __restrict__ O) {
  __shared__ alignas(16) bf16_t Ks[KVB * 128];   // 16KB  [key][d], swizzled
  __shared__ alignas(16) bf16_t Vs[128 * KVB];   // 16KB  [d][key], swizzled
  __shared__ alignas(16) bf16_t Ps[4][16 * KVB]; // 8KB   per-wave P tile [q][key], swizzled
  const int t = threadIdx.x;
  const int lane = t & 63, w = t >> 6;
  const int lr = lane & 15, lg = lane >> 4;
  const int swz = (lr & 7) * 8;  // read-side XOR for rows where row&7 == lr&7
  const int bid = blockIdx.x;
  const int qt = bid & 31;
  const int h = (bid >> 5) & 15;
  const int bb = bid >> 9;
  const int kvh = h >> 2;

  const bf16_t* Qh = Q + (((size_t)bb * 16 + h) * 2048 + qt * 64 + w * 16) * 128;
  const bf16_t* Kh = Kg + ((size_t)bb * 4 + kvh) * 2048 * 128;
  const bf16_t* Vh = Vg + ((size_t)bb * 4 + kvh) * 128 * 2048;

  // staging source indices (pre-swizzled chunk within each row)
  const int krow = t >> 4;                       // 0..15 (16 K-rows per i-group)
  const int kcs = ((t & 15) ^ (krow & 7)) * 8;   // swizzled col chunk, 128-elem row
  const int vrow = t >> 3;                       // 0..31 (32 V-rows per i-group)
  const int vcs = ((t & 7) ^ (vrow & 7)) * 8;    // swizzled col chunk, 64-elem row

  // hoist Q fragments (16 rows x 128 d)
  bf16x8 qf[4];
#pragma unroll
  for (int kc = 0; kc < 4; ++kc)
    qf[kc] = *(const bf16x8*)(Qh + lr * 128 + kc * 32 + lg * 8);

  f32x4 o[8] = {};
  float m2[4] = {-1e30f, -1e30f, -1e30f, -1e30f};
  float ls[4] = {0.f, 0.f, 0.f, 0.f};
  const float sm = 0.08838834764831845f * 1.44269504088896f;  // 1/sqrt(128) * log2(e)

  for (int kb = 0; kb < 2048; kb += KVB) {
    __syncthreads();
#pragma unroll
    for (int i = 0; i < 4; ++i) {
      gload16(Kh + (size_t)(kb + i * 16 + krow) * 128 + kcs, Ks + i * 2048 + t * 8);
      gload16(Vh + (size_t)(i * 32 + vrow) * 2048 + kb + vcs, Vs + i * 2048 + t * 8);
    }
    __syncthreads();

    // QK^T: 4 col-groups x 4 k-chunks  (K row = cg*16+lr -> row&7 == lr&7)
    f32x4 sc[4];
#pragma unroll
    for (int cg = 0; cg < 4; ++cg) {
      f32x4 a = {};
#pragma unroll
      for (int kc = 0; kc < 4; ++kc) {
        bf16x8 kf = *(const bf16x8*)(Ks + (cg * 16 + lr) * 128 + ((kc * 32 + lg * 8) ^ swz));
        a = __builtin_amdgcn_mfma_f32_16x16x32_bf16(qf[kc], kf, a, 0, 0, 0);
      }
      sc[cg] = a * sm;  // now in log2 units
    }
    // online softmax (rows live in 16-lane groups; shuffle masks 1,2,4,8 stay in-group)
    float mx[4];
#pragma unroll
    for (int b = 0; b < 4; ++b) {
      float v = fmaxf(fmaxf(sc[0][b], sc[1][b]), fmaxf(sc[2][b], sc[3][b]));
      v = fmaxf(v, __shfl_xor(v, 1));
      v = fmaxf(v, __shfl_xor(v, 2));
      v = fmaxf(v, __shfl_xor(v, 4));
      v = fmaxf(v, __shfl_xor(v, 8));
      mx[b] = v;
    }
    float resc[4];
#pragma unroll
    for (int b = 0; b < 4; ++b) {
      float mn = fmaxf(m2[b], mx[b]);
      resc[b] = exp2f(m2[b] - mn);
      m2[b] = mn;
    }
    float rs[4] = {0.f, 0.f, 0.f, 0.f};
#pragma unroll
    for (int cg = 0; cg < 4; ++cg)
#pragma unroll
      for (int b = 0; b < 4; ++b) {
        float p = exp2f(sc[cg][b] - m2[b]);
        sc[cg][b] = p;
        rs[b] += p;
      }
#pragma unroll
    for (int b = 0; b < 4; ++b) {
      float v = rs[b];
      v += __shfl_xor(v, 1);
      v += __shfl_xor(v, 2);
      v += __shfl_xor(v, 4);
      v += __shfl_xor(v, 8);
      ls[b] = ls[b] * resc[b] + v;
    }
#pragma unroll
    for (int d = 0; d < 8; ++d)
#pragma unroll
      for (int b = 0; b < 4; ++b) o[d][b] *= resc[b];

    // P: D-layout -> LDS row-major [16][64] (wave-private), swizzled by row&7
    bf16_t* P = Ps[w];
#pragma unroll
    for (int cg = 0; cg < 4; ++cg)
#pragma unroll
      for (int b = 0; b < 4; ++b) {
        int prow = lg * 4 + b;
        P[prow * KVB + ((cg * 16 + lr) ^ ((prow & 7) * 8))] = (bf16_t)sc[cg][b];
      }

    bf16x8 pf[2];
#pragma unroll
    for (int kk = 0; kk < 2; ++kk)   // P row = lr -> row&7 == lr&7
      pf[kk] = *(const bf16x8*)(P + lr * KVB + ((kk * 32 + lg * 8) ^ swz));
#pragma unroll
    for (int d = 0; d < 8; ++d) {
#pragma unroll
      for (int kk = 0; kk < 2; ++kk) {  // V row = d*16+lr -> row&7 == lr&7
        bf16x8 vf = *(const bf16x8*)(Vs + (d * 16 + lr) * KVB + ((kk * 32 + lg * 8) ^ swz));
        o[d] = __builtin_amdgcn_mfma_f32_16x16x32_bf16(pf[kk], vf, o[d], 0, 0, 0);
      }
    }
  }

  // epilogue: divide by l, write (B*S, H) bf16
  const size_t q0 = (size_t)bb * 2048 + qt * 64 + w * 16;
#pragma unroll
  for (int d = 0; d < 8; ++d)
#pragma unroll
    for (int b = 0; b < 4; ++b) {
      float val = o[d][b] / ls[b];
      O[(q0 + lg * 4 + b) * 2048 + h * 128 + d * 16 + lr] = (bf16_t)val;
    }
}

// ---------------------------------------------------------------- launch
extern "C" void kernel_launch(void* const* d_in, const int* in_sizes, int n_in,
                              void* d_out, int out_size, void* d_ws, size_t ws_size,
                              hipStream_t stream) {
  const float* hs = (const float*)d_in[0];
  const float* fc = (const float*)d_in[1];
  const float* fs = (const float*)d_in[2];
  const float* Wq = (const float*)d_in[3];
  const float* Wk = (const float*)d_in[4];
  const float* Wv = (const float*)d_in[5];
  const float* Wo = (const float*)d_in[6];
  float* out = (float*)d_out;

  char* ws = (char*)d_ws;
  bf16_t* hs_b = (bf16_t*)ws;                      // 16,777,216 B
  bf16_t* wcat = (bf16_t*)(ws + 16777216);         // 12,582,912 B (3072x2048)
  bf16_t* wo_b = (bf16_t*)(ws + 29360128);         //  8,388,608 B
  float* qkv = (float*)(ws + 37748736);            // 50,331,648 B (4096x3072)
  bf16_t* qr = (bf16_t*)(ws + 88080384);           // 16,777,216 B
  bf16_t* kr = (bf16_t*)(ws + 104857600);          //  4,194,304 B
  bf16_t* vt = (bf16_t*)(ws + 109051904);          //  4,194,304 B
  bf16_t* ao = (bf16_t*)(ws + 113246208);          // 16,777,216 B  (total ~124 MB)

  cvt_kernel<<<8388608 / 8 / 256, 256, 0, stream>>>(hs, hs_b, 8388608 / 8);
  cvt_kernel<<<4194304 / 8 / 256, 256, 0, stream>>>(Wq, wcat, 4194304 / 8);
  cvt_kernel<<<1048576 / 8 / 256, 256, 0, stream>>>(Wk, wcat + 4194304, 1048576 / 8);
  cvt_kernel<<<1048576 / 8 / 256, 256, 0, stream>>>(Wv, wcat + 5242880, 1048576 / 8);
  cvt_kernel<<<4194304 / 8 / 256, 256, 0, stream>>>(Wo, wo_b, 4194304 / 8);

  dim3 g1(3072 / BN, 4096 / BM);
  gemm_bt<<<g1, 256, 0, stream>>>(hs_b, wcat, qkv, 4096, 3072, 2048);

  rope_kernel<<<4096, 256, 0, stream>>>(qkv, fc, fs, qr, 16, 4, 0);
  rope_kernel<<<1024, 256, 0, stream>>>(qkv, fc, fs, kr, 4, 2, 2048);
  vt_kernel<<<256, 256, 0, stream>>>(qkv, vt);

  attn_kernel<<<1024, 256, 0, stream>>>(qr, kr, vt, ao);

  dim3 g2(2048 / BN, 4096 / BM);
  gemm_bt<<<g2, 256, 0, stream>>>(ao, wo_b, out, 4096, 2048, 2048);
}

// Round 3
// 291.370 us; speedup vs baseline: 1.4281x; 1.0574x over previous
//
#include <hip/hip_runtime.h>

typedef __bf16 bf16_t;
typedef bf16_t bf16x8 __attribute__((ext_vector_type(8)));
typedef float f32x4 __attribute__((ext_vector_type(4)));

typedef const __attribute__((address_space(1))) void* as1_cvp;
typedef __attribute__((address_space(3))) void* as3_vp;

__device__ __forceinline__ void gload16(const void* g, void* l) {
  __builtin_amdgcn_global_load_lds((as1_cvp)g, (as3_vp)l, 16, 0, 0);
}

// ---------------------------------------------------------------- convert f32 -> bf16
__global__ __launch_bounds__(256) void cvt_kernel(const float* __restrict__ src,
                                                  bf16_t* __restrict__ dst, int n8) {
  int i = blockIdx.x * 256 + threadIdx.x;
  if (i >= n8) return;
  int idx = i * 8;
  float4 a = *(const float4*)(src + idx);
  float4 b = *(const float4*)(src + idx + 4);
  bf16x8 o;
  o[0] = (bf16_t)a.x; o[1] = (bf16_t)a.y; o[2] = (bf16_t)a.z; o[3] = (bf16_t)a.w;
  o[4] = (bf16_t)b.x; o[5] = (bf16_t)b.y; o[6] = (bf16_t)b.z; o[7] = (bf16_t)b.w;
  *(bf16x8*)(dst + idx) = o;
}

// ---------------------------------------------------------------- GEMM  C = A * B^T
// A: MxK bf16 row-major, B: NxK bf16 row-major (i.e. B^T input), C: MxN f32
// 128x128 tile, BK=64, 256 threads (4 waves, 2x2), m97 structure.
#define BM 128
#define BN 128
#define BK 64
__global__ __launch_bounds__(256, 2) void gemm_bt(const bf16_t* __restrict__ A,
                                                  const bf16_t* __restrict__ B,
                                                  float* __restrict__ C,
                                                  int M, int N, int K) {
  __shared__ alignas(16) bf16_t As[BM * BK];
  __shared__ alignas(16) bf16_t Bs[BN * BK];
  const int t = threadIdx.x;
  const int lane = t & 63, w = t >> 6;
  const int wm = w >> 1, wn = w & 1;
  const int lr = lane & 15, lg = lane >> 4;
  const int m0 = blockIdx.y * BM, n0 = blockIdx.x * BN;
  const int srow = t >> 3, scol = (t & 7) * 8;  // staging: row within 32-group, col chunk

  f32x4 acc[4][4] = {};

  for (int kb = 0; kb < K; kb += BK) {
    __syncthreads();
#pragma unroll
    for (int i = 0; i < 4; ++i) {
      gload16(A + (size_t)(m0 + srow + 32 * i) * K + kb + scol, As + i * 2048 + t * 8);
      gload16(B + (size_t)(n0 + srow + 32 * i) * K + kb + scol, Bs + i * 2048 + t * 8);
    }
    __syncthreads();
#pragma unroll
    for (int kk = 0; kk < 2; ++kk) {
      const int ko = kk * 32 + lg * 8;
      bf16x8 af[4], bfr[4];
#pragma unroll
      for (int r = 0; r < 4; ++r)
        af[r] = *(const bf16x8*)(As + (wm * 64 + r * 16 + lr) * BK + ko);
#pragma unroll
      for (int c = 0; c < 4; ++c)
        bfr[c] = *(const bf16x8*)(Bs + (wn * 64 + c * 16 + lr) * BK + ko);
#pragma unroll
      for (int r = 0; r < 4; ++r)
#pragma unroll
        for (int c = 0; c < 4; ++c)
          acc[r][c] = __builtin_amdgcn_mfma_f32_16x16x32_bf16(af[r], bfr[c], acc[r][c], 0, 0, 0);
    }
  }
  // epilogue: D layout row=(lane>>4)*4+b, col=lane&15
#pragma unroll
  for (int r = 0; r < 4; ++r)
#pragma unroll
    for (int c = 0; c < 4; ++c)
#pragma unroll
      for (int b = 0; b < 4; ++b)
        C[(size_t)(m0 + wm * 64 + r * 16 + lg * 4 + b) * N + n0 + wn * 64 + c * 16 + lr] =
            acc[r][c][b];
}

// ---------------------------------------------------------------- RoPE + relayout (Q or K)
// src: qkv f32 (4096 x 3072), dst: (B, nh, S, HD) bf16
__global__ __launch_bounds__(256) void rope_kernel(const float* __restrict__ qkv,
                                                   const float* __restrict__ cs,
                                                   const float* __restrict__ sn,
                                                   bf16_t* __restrict__ dst,
                                                   int nh, int lognh, int col_off) {
  int idx = blockIdx.x * 256 + threadIdx.x;
  int chunk = idx & 15;            // 16 chunks of 8 elems (=4 pairs) over HD=128
  int s = (idx >> 4) & 2047;
  int hh = (idx >> 15) & (nh - 1);
  int bb = idx >> (15 + lognh);
  const float* src = qkv + (size_t)(bb * 2048 + s) * 3072 + col_off + hh * 128 + chunk * 8;
  float4 x0 = *(const float4*)src;
  float4 x1 = *(const float4*)(src + 4);
  float4 c4 = *(const float4*)(cs + s * 64 + chunk * 4);
  float4 s4 = *(const float4*)(sn + s * 64 + chunk * 4);
  bf16x8 o;
  o[0] = (bf16_t)(x0.x * c4.x - x0.y * s4.x);
  o[1] = (bf16_t)(x0.x * s4.x + x0.y * c4.x);
  o[2] = (bf16_t)(x0.z * c4.y - x0.w * s4.y);
  o[3] = (bf16_t)(x0.z * s4.y + x0.w * c4.y);
  o[4] = (bf16_t)(x1.x * c4.z - x1.y * s4.z);
  o[5] = (bf16_t)(x1.x * s4.z + x1.y * c4.z);
  o[6] = (bf16_t)(x1.z * c4.w - x1.w * s4.w);
  o[7] = (bf16_t)(x1.z * s4.w + x1.w * c4.w);
  *(bf16x8*)(dst + ((size_t)(bb * nh + hh) * 2048 + s) * 128 + chunk * 8) = o;
}

// ---------------------------------------------------------------- V transpose: (B,S,[v cols]) -> (B,NKV,HD,S) bf16
__global__ __launch_bounds__(256) void vt_kernel(const float* __restrict__ qkv,
                                                 bf16_t* __restrict__ vt) {
  __shared__ bf16_t tile[64][128];
  int t = threadIdx.x;
  int bid = blockIdx.x;  // (bb*4 + kh)*32 + st
  int st = bid & 31;
  int kh = (bid >> 5) & 3;
  int bb = bid >> 7;
  const float* src = qkv + (size_t)(bb * 2048 + st * 64) * 3072 + 2560 + kh * 128;
#pragma unroll
  for (int j = 0; j < 8; ++j) {
    int id = t + 256 * j;  // 2048 float4 chunks: 64 rows x 32 fvec
    int sr = id >> 5, dv = id & 31;
    float4 x = *(const float4*)(src + (size_t)sr * 3072 + dv * 4);
    tile[sr][dv * 4 + 0] = (bf16_t)x.x;
    tile[sr][dv * 4 + 1] = (bf16_t)x.y;
    tile[sr][dv * 4 + 2] = (bf16_t)x.z;
    tile[sr][dv * 4 + 3] = (bf16_t)x.w;
  }
  __syncthreads();
  bf16_t* dst = vt + (size_t)(bb * 4 + kh) * 128 * 2048 + st * 64;
#pragma unroll
  for (int j = 0; j < 4; ++j) {
    int id = t + 256 * j;  // 1024 chunks of 8 bf16: 128 d x 8 s-chunks
    int d = id >> 3, sc8 = id & 7;
    bf16x8 v;
#pragma unroll
    for (int e = 0; e < 8; ++e) v[e] = tile[sc8 * 8 + e][d];
    *(bf16x8*)(dst + (size_t)d * 2048 + sc8 * 8) = v;
  }
}

// ---------------------------------------------------------------- flash attention
// Q:(B,NH,S,HD) K:(B,NKV,S,HD) Vt:(B,NKV,HD,S) all bf16 -> O:(B*S, H) bf16
// 4 waves/block, each wave owns 32 q-rows (2 row-groups); KVB=64 double-buffered
// in LDS, 2-phase pipeline (T3-min): STAGE(next) issued before compute(cur),
// one vmcnt-drain barrier per tile. XOR-swizzled LDS per rule #21.
// T13 defer-rescale (thr=8 in log2 units), T5 setprio around MFMA clusters.
#define KVB 64
__global__ __launch_bounds__(256, 2) void attn_kernel(const bf16_t* __restrict__ Q,
                                                      const bf16_t* __restrict__ Kg,
                                                      const bf16_t* __restrict__ Vg,
                                                      bf16_t* __restrict__ O) {
  __shared__ alignas(16) bf16_t Ks[2][KVB * 128];   // 32KB  [key][d], swizzled
  __shared__ alignas(16) bf16_t Vs[2][128 * KVB];   // 32KB  [d][key], swizzled
  __shared__ alignas(16) bf16_t Ps[4][32 * KVB];    // 16KB  per-wave P [q][key], swizzled
  const int t = threadIdx.x;
  const int lane = t & 63, w = t >> 6;
  const int lr = lane & 15, lg = lane >> 4;
  const int swz = (lr & 7) * 8;  // read-side XOR (row&7 == lr&7 for all fragment reads)
  const int bid = blockIdx.x;
  const int qt = bid & 15;
  const int h = (bid >> 4) & 15;
  const int bb = bid >> 8;
  const int kvh = h >> 2;

  const bf16_t* Qh = Q + (((size_t)bb * 16 + h) * 2048 + qt * 128 + w * 32) * 128;
  const bf16_t* Kh = Kg + ((size_t)bb * 4 + kvh) * 2048 * 128;
  const bf16_t* Vh = Vg + ((size_t)bb * 4 + kvh) * 128 * 2048;

  // staging source indices (pre-swizzled chunk within each row)
  const int krow = t >> 4;                       // 0..15 (16 K-rows per i-group)
  const int kcs = ((t & 15) ^ (krow & 7)) * 8;   // swizzled col chunk, 128-elem row
  const int vrow = t >> 3;                       // 0..31 (32 V-rows per i-group)
  const int vcs = ((t & 7) ^ (vrow & 7)) * 8;    // swizzled col chunk, 64-elem row

  // hoist Q fragments (2 row-groups x 16 rows x 128 d)
  bf16x8 qf[2][4];
#pragma unroll
  for (int rg = 0; rg < 2; ++rg)
#pragma unroll
    for (int kc = 0; kc < 4; ++kc)
      qf[rg][kc] = *(const bf16x8*)(Qh + (rg * 16 + lr) * 128 + kc * 32 + lg * 8);

  f32x4 o[2][8] = {};
  float m2[2][4], ls[2][4];
#pragma unroll
  for (int rg = 0; rg < 2; ++rg)
#pragma unroll
    for (int b = 0; b < 4; ++b) { m2[rg][b] = -1e30f; ls[rg][b] = 0.f; }
  const float sm = 0.08838834764831845f * 1.44269504088896f;  // 1/sqrt(128) * log2(e)

#define STAGE(buf, kb)                                                                   \
  _Pragma("unroll") for (int i = 0; i < 4; ++i) {                                        \
    gload16(Kh + (size_t)((kb) + i * 16 + krow) * 128 + kcs, &Ks[buf][i * 2048 + t * 8]);\
    gload16(Vh + (size_t)(i * 32 + vrow) * 2048 + (kb) + vcs, &Vs[buf][i * 2048 + t * 8]);\
  }

  STAGE(0, 0);
  __syncthreads();

  for (int tt = 0; tt < 32; ++tt) {
    const int cur = tt & 1;
    if (tt < 31) { STAGE(cur ^ 1, (tt + 1) * KVB); }
    const bf16_t* Kc = Ks[cur];
    const bf16_t* Vc = Vs[cur];

    // QK^T: 4 col-groups x 4 k-chunks, kf reused across both row-groups
    f32x4 sc[2][4];
    __builtin_amdgcn_s_setprio(1);
#pragma unroll
    for (int cg = 0; cg < 4; ++cg) {
      f32x4 a0 = {}, a1 = {};
#pragma unroll
      for (int kc = 0; kc < 4; ++kc) {
        bf16x8 kf = *(const bf16x8*)(Kc + (cg * 16 + lr) * 128 + ((kc * 32 + lg * 8) ^ swz));
        a0 = __builtin_amdgcn_mfma_f32_16x16x32_bf16(qf[0][kc], kf, a0, 0, 0, 0);
        a1 = __builtin_amdgcn_mfma_f32_16x16x32_bf16(qf[1][kc], kf, a1, 0, 0, 0);
      }
      sc[0][cg] = a0 * sm;  // log2 units
      sc[1][cg] = a1 * sm;
    }
    __builtin_amdgcn_s_setprio(0);

    // online softmax per row-group (rows live in 16-lane groups)
#pragma unroll
    for (int rg = 0; rg < 2; ++rg) {
      float mx[4];
#pragma unroll
      for (int b = 0; b < 4; ++b) {
        float v = fmaxf(fmaxf(sc[rg][0][b], sc[rg][1][b]), fmaxf(sc[rg][2][b], sc[rg][3][b]));
        v = fmaxf(v, __shfl_xor(v, 1));
        v = fmaxf(v, __shfl_xor(v, 2));
        v = fmaxf(v, __shfl_xor(v, 4));
        v = fmaxf(v, __shfl_xor(v, 8));
        mx[b] = v;
      }
      // T13: rescale only if some row's max grew by > 8 (log2) -> P bounded by 256
      bool need = false;
#pragma unroll
      for (int b = 0; b < 4; ++b) need = need || (mx[b] > m2[rg][b] + 8.0f);
      if (__any(need)) {
#pragma unroll
        for (int b = 0; b < 4; ++b) {
          float mn = fmaxf(m2[rg][b], mx[b]);
          float resc = exp2f(m2[rg][b] - mn);
          m2[rg][b] = mn;
          ls[rg][b] *= resc;
#pragma unroll
          for (int d = 0; d < 8; ++d) o[rg][d][b] *= resc;
        }
      }
      float rs[4] = {0.f, 0.f, 0.f, 0.f};
#pragma unroll
      for (int cg = 0; cg < 4; ++cg)
#pragma unroll
        for (int b = 0; b < 4; ++b) {
          float p = exp2f(sc[rg][cg][b] - m2[rg][b]);
          sc[rg][cg][b] = p;
          rs[b] += p;
        }
#pragma unroll
      for (int b = 0; b < 4; ++b) {
        float v = rs[b];
        v += __shfl_xor(v, 1);
        v += __shfl_xor(v, 2);
        v += __shfl_xor(v, 4);
        v += __shfl_xor(v, 8);
        ls[rg][b] += v;
      }
    }

    // P: D-layout -> LDS row-major [32][64] (wave-private), swizzled by row&7
    bf16_t* P = Ps[w];
#pragma unroll
    for (int rg = 0; rg < 2; ++rg)
#pragma unroll
      for (int cg = 0; cg < 4; ++cg)
#pragma unroll
        for (int b = 0; b < 4; ++b) {
          int prow = rg * 16 + lg * 4 + b;
          P[prow * KVB + ((cg * 16 + lr) ^ ((prow & 7) * 8))] = (bf16_t)sc[rg][cg][b];
        }

    bf16x8 pf[2][2];
#pragma unroll
    for (int rg = 0; rg < 2; ++rg)
#pragma unroll
      for (int kk = 0; kk < 2; ++kk)  // P row = rg*16+lr -> row&7 == lr&7
        pf[rg][kk] = *(const bf16x8*)(P + (rg * 16 + lr) * KVB + ((kk * 32 + lg * 8) ^ swz));

    __builtin_amdgcn_s_setprio(1);
#pragma unroll
    for (int d = 0; d < 8; ++d) {
#pragma unroll
      for (int kk = 0; kk < 2; ++kk) {  // V row = d*16+lr -> row&7 == lr&7
        bf16x8 vf = *(const bf16x8*)(Vc + (d * 16 + lr) * KVB + ((kk * 32 + lg * 8) ^ swz));
        o[0][d] = __builtin_amdgcn_mfma_f32_16x16x32_bf16(pf[0][kk], vf, o[0][d], 0, 0, 0);
        o[1][d] = __builtin_amdgcn_mfma_f32_16x16x32_bf16(pf[1][kk], vf, o[1][d], 0, 0, 0);
      }
    }
    __builtin_amdgcn_s_setprio(0);
    __syncthreads();  // drains vmcnt -> next tile's K/V ready; P/V reads done for rewrite
  }

  // epilogue: divide by l, write (B*S, H) bf16
  const size_t q0 = (size_t)bb * 2048 + qt * 128 + w * 32;
#pragma unroll
  for (int rg = 0; rg < 2; ++rg)
#pragma unroll
    for (int d = 0; d < 8; ++d)
#pragma unroll
      for (int b = 0; b < 4; ++b) {
        float val = o[rg][d][b] / ls[rg][b];
        O[(q0 + rg * 16 + lg * 4 + b) * 2048 + h * 128 + d * 16 + lr] = (bf16_t)val;
      }
}

// ---------------------------------------------------------------- launch
extern "C" void kernel_launch(void* const* d_in, const int* in_sizes, int n_in,
                              void* d_out, int out_size, void* d_ws, size_t ws_size,
                              hipStream_t stream) {
  const float* hs = (const float*)d_in[0];
  const float* fc = (const float*)d_in[1];
  const float* fs = (const float*)d_in[2];
  const float* Wq = (const float*)d_in[3];
  const float* Wk = (const float*)d_in[4];
  const float* Wv = (const float*)d_in[5];
  const float* Wo = (const float*)d_in[6];
  float* out = (float*)d_out;

  char* ws = (char*)d_ws;
  bf16_t* hs_b = (bf16_t*)ws;                      // 16,777,216 B
  bf16_t* wcat = (bf16_t*)(ws + 16777216);         // 12,582,912 B (3072x2048)
  bf16_t* wo_b = (bf16_t*)(ws + 29360128);         //  8,388,608 B
  float* qkv = (float*)(ws + 37748736);            // 50,331,648 B (4096x3072)
  bf16_t* qr = (bf16_t*)(ws + 88080384);           // 16,777,216 B
  bf16_t* kr = (bf16_t*)(ws + 104857600);          //  4,194,304 B
  bf16_t* vt = (bf16_t*)(ws + 109051904);          //  4,194,304 B
  bf16_t* ao = (bf16_t*)(ws + 113246208);          // 16,777,216 B  (total ~124 MB)

  cvt_kernel<<<8388608 / 8 / 256, 256, 0, stream>>>(hs, hs_b, 8388608 / 8);
  cvt_kernel<<<4194304 / 8 / 256, 256, 0, stream>>>(Wq, wcat, 4194304 / 8);
  cvt_kernel<<<1048576 / 8 / 256, 256, 0, stream>>>(Wk, wcat + 4194304, 1048576 / 8);
  cvt_kernel<<<1048576 / 8 / 256, 256, 0, stream>>>(Wv, wcat + 5242880, 1048576 / 8);
  cvt_kernel<<<4194304 / 8 / 256, 256, 0, stream>>>(Wo, wo_b, 4194304 / 8);

  dim3 g1(3072 / BN, 4096 / BM);
  gemm_bt<<<g1, 256, 0, stream>>>(hs_b, wcat, qkv, 4096, 3072, 2048);

  rope_kernel<<<4096, 256, 0, stream>>>(qkv, fc, fs, qr, 16, 4, 0);
  rope_kernel<<<1024, 256, 0, stream>>>(qkv, fc, fs, kr, 4, 2, 2048);
  vt_kernel<<<256, 256, 0, stream>>>(qkv, vt);

  attn_kernel<<<512, 256, 0, stream>>>(qr, kr, vt, ao);

  dim3 g2(2048 / BN, 4096 / BM);
  gemm_bt<<<g2, 256, 0, stream>>>(ao, wo_b, out, 4096, 2048, 2048);
}